// Round 7
// baseline (2431.518 us; speedup 1.0000x reference)
//
#include <hip/hip_runtime.h>
#include <math.h>

// x: [T=8, B=16, Cin=64, H=64, W=64] fp32
// W: [Cout=128, Cin=64, 3, 3] fp32
// out: spikes [T, B, Cout, H, W] fp32 (0.0 / 1.0)
//
// Precision: output is Heaviside(v-1) vs precision-neutral (fp64) numpy ref;
// all conv accumulation + LIF decisions must be fp64 (R2: absmax 0.0).
//
// R6: f64 MFMA conv with runtime-probed D layout -> MfmaUtil 57.5%, conv
// 1832 us; idle 42% = per-chunk stage/barrier drains (4 chunks).
// R7: stage ALL 64 ci as fp32 in LDS (45 KB) once per block; K-loop of 144
// steps / 1152 MFMAs runs with no barriers; B = ds_read_b32 + cvt_f64_f32
// (bit-identical doubles, same summation order => absmax 0.0 preserved).
#define TT 8
#define BB 16
#define CIN 64
#define COUT 128
#define HH 64
#define WW 64

#define PW 16
#define PH 8
#define XS_W2 (PW + 2)                     // 18
#define XS_H2 (PH + 2)                     // 10
#define XS_ROW (XS_H2 * XS_W2)             // 180 floats per ci
#define XS_N (CIN * XS_ROW)                // 11520 floats = 45 KB

#define W_ELEMS (CIN * 9 * COUT)           // 73728
#define W_BYTES ((size_t)W_ELEMS * 8)      // 589824
#define NPLANE (BB * COUT * HH * WW)       // 8388608 per t-plane
#define Z_BYTES ((size_t)TT * NPLANE * 8)  // 512 MB
#define FLAG_OFF (W_BYTES + Z_BYTES)
#define WS_NEED (FLAG_OFF + 16)

typedef double d4 __attribute__((ext_vector_type(4)));

// ---- prologue: W [co][ci][kh][kw] fp32 -> wd [k=(ci,kh,kw)][co] fp64 ----
__global__ void wconv_f64(const float* __restrict__ Wt, double* __restrict__ wd) {
    int idx = blockIdx.x * 256 + threadIdx.x;
    if (idx >= W_ELEMS) return;
    int co = idx & 127;
    int k = idx >> 7;
    int ci = k / 9;
    int r = k - ci * 9;
    wd[idx] = (double)Wt[((size_t)co * CIN + ci) * 9 + r];
}

// ---- probe: discover f64 MFMA D layout on this hardware (R6-proven) ----
__global__ void mfma_probe(int* __restrict__ flag) {
    int lane = threadIdx.x;
    int l15 = lane & 15, q = lane >> 4;
    double a = (double)(l15 * 4 + q + 1);             // A[m][k] = m*4+k+1
    double b = (double)(q * 16 + l15 + 1) * 0.001;    // B[k][n] = (k*16+n+1)/1000
    d4 acc = (d4)(0.0);
    acc = __builtin_amdgcn_mfma_f64_16x16x4f64(a, b, acc, 0, 0, 0);
    bool ok0 = true, ok1 = true, ok2 = true, ok3 = true;
    for (int d = 0; d < 4; ++d) {
        double e0 = 0, e1 = 0, e2 = 0, e3 = 0;
        for (int k = 0; k < 4; ++k) {
            e0 += (double)((4 * q + d) * 4 + k + 1) * ((double)(k * 16 + l15 + 1) * 0.001);
            e1 += (double)(l15 * 4 + k + 1) * ((double)(k * 16 + 4 * q + d + 1) * 0.001);
            e2 += (double)((q + 4 * d) * 4 + k + 1) * ((double)(k * 16 + l15 + 1) * 0.001);
            e3 += (double)(l15 * 4 + k + 1) * ((double)(k * 16 + q + 4 * d + 1) * 0.001);
        }
        ok0 &= fabs(acc[d] - e0) < 1e-9;
        ok1 &= fabs(acc[d] - e1) < 1e-9;
        ok2 &= fabs(acc[d] - e2) < 1e-9;
        ok3 &= fabs(acc[d] - e3) < 1e-9;
    }
    int f = __all(ok0) ? 0 : (__all(ok1) ? 1 : (__all(ok2) ? 2 : (__all(ok3) ? 3 : 4)));
    if (lane == 0) *flag = f;
}

// ---- phase 1a: implicit-GEMM conv via fp64 MFMA, barrier-free K-loop ----
// Block: 4 waves, 64 co x 128 px per block, one image.
// Grid: (4, 8, 2 * 128) = 8192 blocks.
__global__ __launch_bounds__(256)
void conv_mfma(const float* __restrict__ x, const double* __restrict__ wd,
               double* __restrict__ z, const int* __restrict__ flag) {
    const int lay = *flag;
    if (lay > 3) return;

    __shared__ float xs[XS_N];

    const int tid = threadIdx.x;
    const int lane = tid & 63;
    const int wave = tid >> 6;
    const int l15 = lane & 15;
    const int koff = lane >> 4;
    const int cslice = wave & 1;
    const int pslice = wave >> 1;
    const int hbase = 4 * pslice;

    const int w0 = blockIdx.x * PW;
    const int h0 = blockIdx.y * PH;
    const int cob = (blockIdx.z & 1) * 64;
    const int tb = blockIdx.z >> 1;
    const int co_w = cob + 32 * cslice;

    const float* xb = x + (size_t)tb * (CIN * HH * WW);

    // ---- stage all 64 ci as fp32 with zero halo (one barrier total) ----
    for (int idx = tid; idx < XS_N; idx += 256) {
        int cil = idx / XS_ROW;
        int rem = idx - cil * XS_ROW;
        int hr = rem / XS_W2;
        int wr = rem - hr * XS_W2;
        int gh = h0 - 1 + hr;
        int gw = w0 - 1 + wr;
        float val = 0.0f;
        if (gh >= 0 && gh < HH && gw >= 0 && gw < WW)
            val = xb[cil * (HH * WW) + gh * WW + gw];
        xs[idx] = val;
    }
    __syncthreads();

    d4 acc[2][4];
#pragma unroll
    for (int i = 0; i < 2; ++i)
#pragma unroll
        for (int j = 0; j < 4; ++j)
            acc[i][j] = (d4)(0.0);

    // K = 576 (ci*9 + kh*3 + kw), 144 steps of 4; regs double-buffered.
    double a_cur0, a_cur1, b_cur0, b_cur1, b_cur2, b_cur3;
    double a_nxt0, a_nxt1, b_nxt0, b_nxt1, b_nxt2, b_nxt3;
    {
        int kl = koff;
        int cil = kl / 9;
        int r = kl - cil * 9;
        int kh = r / 3;
        int kw = r - kh * 3;
        const double* ap = wd + (size_t)kl * COUT + co_w + l15;
        a_cur0 = ap[0]; a_cur1 = ap[16];
        const float* bp = xs + cil * XS_ROW + (hbase + kh) * XS_W2 + l15 + kw;
        b_cur0 = (double)bp[0]; b_cur1 = (double)bp[XS_W2];
        b_cur2 = (double)bp[2 * XS_W2]; b_cur3 = (double)bp[3 * XS_W2];
    }
    for (int ks = 0; ks < 143; ++ks) {
        {
            int kl = (ks + 1) * 4 + koff;
            int cil = kl / 9;
            int r = kl - cil * 9;
            int kh = r / 3;
            int kw = r - kh * 3;
            const double* ap = wd + (size_t)kl * COUT + co_w + l15;
            a_nxt0 = ap[0]; a_nxt1 = ap[16];
            const float* bp = xs + cil * XS_ROW + (hbase + kh) * XS_W2 + l15 + kw;
            b_nxt0 = (double)bp[0]; b_nxt1 = (double)bp[XS_W2];
            b_nxt2 = (double)bp[2 * XS_W2]; b_nxt3 = (double)bp[3 * XS_W2];
        }
        acc[0][0] = __builtin_amdgcn_mfma_f64_16x16x4f64(a_cur0, b_cur0, acc[0][0], 0, 0, 0);
        acc[0][1] = __builtin_amdgcn_mfma_f64_16x16x4f64(a_cur0, b_cur1, acc[0][1], 0, 0, 0);
        acc[0][2] = __builtin_amdgcn_mfma_f64_16x16x4f64(a_cur0, b_cur2, acc[0][2], 0, 0, 0);
        acc[0][3] = __builtin_amdgcn_mfma_f64_16x16x4f64(a_cur0, b_cur3, acc[0][3], 0, 0, 0);
        acc[1][0] = __builtin_amdgcn_mfma_f64_16x16x4f64(a_cur1, b_cur0, acc[1][0], 0, 0, 0);
        acc[1][1] = __builtin_amdgcn_mfma_f64_16x16x4f64(a_cur1, b_cur1, acc[1][1], 0, 0, 0);
        acc[1][2] = __builtin_amdgcn_mfma_f64_16x16x4f64(a_cur1, b_cur2, acc[1][2], 0, 0, 0);
        acc[1][3] = __builtin_amdgcn_mfma_f64_16x16x4f64(a_cur1, b_cur3, acc[1][3], 0, 0, 0);
        a_cur0 = a_nxt0; a_cur1 = a_nxt1;
        b_cur0 = b_nxt0; b_cur1 = b_nxt1; b_cur2 = b_nxt2; b_cur3 = b_nxt3;
    }
    acc[0][0] = __builtin_amdgcn_mfma_f64_16x16x4f64(a_cur0, b_cur0, acc[0][0], 0, 0, 0);
    acc[0][1] = __builtin_amdgcn_mfma_f64_16x16x4f64(a_cur0, b_cur1, acc[0][1], 0, 0, 0);
    acc[0][2] = __builtin_amdgcn_mfma_f64_16x16x4f64(a_cur0, b_cur2, acc[0][2], 0, 0, 0);
    acc[0][3] = __builtin_amdgcn_mfma_f64_16x16x4f64(a_cur0, b_cur3, acc[0][3], 0, 0, 0);
    acc[1][0] = __builtin_amdgcn_mfma_f64_16x16x4f64(a_cur1, b_cur0, acc[1][0], 0, 0, 0);
    acc[1][1] = __builtin_amdgcn_mfma_f64_16x16x4f64(a_cur1, b_cur1, acc[1][1], 0, 0, 0);
    acc[1][2] = __builtin_amdgcn_mfma_f64_16x16x4f64(a_cur1, b_cur2, acc[1][2], 0, 0, 0);
    acc[1][3] = __builtin_amdgcn_mfma_f64_16x16x4f64(a_cur1, b_cur3, acc[1][3], 0, 0, 0);

    // ---- store z with probed D layout ----
    double* zb = z + (size_t)tb * (COUT * HH * WW);
#pragma unroll
    for (int i2 = 0; i2 < 2; ++i2) {
        int cw = co_w + 16 * i2;
#pragma unroll
        for (int jt = 0; jt < 4; ++jt) {
            int h = h0 + hbase + jt;
            d4 a = acc[i2][jt];
            if (lay == 0) {          // D[m=4q+d][n=l15]
#pragma unroll
                for (int d = 0; d < 4; ++d)
                    zb[(size_t)(cw + 4 * koff + d) * (HH * WW) + h * WW + w0 + l15] = a[d];
            } else if (lay == 1) {   // D[m=l15][n=4q+d]
                *(d4*)&zb[(size_t)(cw + l15) * (HH * WW) + h * WW + w0 + 4 * koff] = a;
            } else if (lay == 2) {   // D[m=q+4d][n=l15]
#pragma unroll
                for (int d = 0; d < 4; ++d)
                    zb[(size_t)(cw + koff + 4 * d) * (HH * WW) + h * WW + w0 + l15] = a[d];
            } else {                 // D[m=l15][n=q+4d]
#pragma unroll
                for (int d = 0; d < 4; ++d)
                    zb[(size_t)(cw + l15) * (HH * WW) + h * WW + w0 + koff + 4 * d] = a[d];
            }
        }
    }
}

// ---- phase 1b: trusted vector-fp64 conv (runs iff probe found no layout) ----
#define VTILE_H 4
#define VTILE_W 16
#define VXS_W (VTILE_W + 2)
#define VXS_ROW ((VTILE_H + 2) * VXS_W)    // 108 per ci
#define VXS_N (CIN * VXS_ROW)
__global__ __launch_bounds__(256, 2)
void conv_f64(const float* __restrict__ x, const double* __restrict__ wd,
              double* __restrict__ z, const int* __restrict__ flag) {
    if (*flag <= 3) return;
    __shared__ float xs[VXS_N];

    const int tid = threadIdx.x;
    const int pt = tid & 15;
    const int cg = tid >> 4;
    const int w0 = blockIdx.x * VTILE_W;
    const int h0 = blockIdx.y * VTILE_H;
    const int tb = blockIdx.z;
    const int co_base = cg * 8;

    const float* xb = x + (size_t)tb * (CIN * HH * WW);
    for (int idx = tid; idx < VXS_N; idx += 256) {
        int ci = idx / VXS_ROW;
        int rem = idx - ci * VXS_ROW;
        int hh = rem / VXS_W;
        int ww2 = rem - hh * VXS_W;
        int gh = h0 - 1 + hh;
        int gw = w0 - 1 + ww2;
        float val = 0.0f;
        if (gh >= 0 && gh < HH && gw >= 0 && gw < WW)
            val = xb[ci * (HH * WW) + gh * WW + gw];
        xs[idx] = val;
    }
    __syncthreads();

    double acc[32];
#pragma unroll
    for (int i = 0; i < 32; ++i) acc[i] = 0.0;

    for (int ci = 0; ci < CIN; ++ci) {
        const float* xr = xs + ci * VXS_ROW;
        const double* wrow = wd + (size_t)(ci * 9) * COUT + co_base;
#pragma unroll
        for (int kh = 0; kh < 3; ++kh) {
#pragma unroll
            for (int kw = 0; kw < 3; ++kw) {
                const double2* wp = (const double2*)(wrow + (kh * 3 + kw) * COUT);
                double2 w01 = wp[0], w23 = wp[1], w45 = wp[2], w67 = wp[3];
                double wv[8] = {w01.x, w01.y, w23.x, w23.y,
                                w45.x, w45.y, w67.x, w67.y};
                double xv[4];
#pragma unroll
                for (int j = 0; j < 4; ++j)
                    xv[j] = (double)xr[(j + kh) * VXS_W + pt + kw];
#pragma unroll
                for (int i = 0; i < 8; ++i) {
#pragma unroll
                    for (int j = 0; j < 4; ++j)
                        acc[i * 4 + j] = fma(wv[i], xv[j], acc[i * 4 + j]);
                }
            }
        }
    }

    double* zb = z + (size_t)tb * (COUT * HH * WW);
#pragma unroll
    for (int i = 0; i < 8; ++i) {
#pragma unroll
        for (int j = 0; j < 4; ++j)
            zb[(size_t)(co_base + i) * (HH * WW) + (h0 + j) * WW + (w0 + pt)]
                = acc[i * 4 + j];
    }
}

// ---- phase 2: LIF scan over t, 4 elems/thread ----
__global__ __launch_bounds__(256)
void lif_scan(const double* __restrict__ z, float* __restrict__ out) {
    size_t n = ((size_t)blockIdx.x * 256 + threadIdx.x) * 4;
    double v0 = 0.0, v1 = 0.0, v2 = 0.0, v3 = 0.0;
#pragma unroll
    for (int t = 0; t < TT; ++t) {
        const double* zp = z + (size_t)t * NPLANE + n;
        double2 za = *(const double2*)(zp);
        double2 zc = *(const double2*)(zp + 2);
        v0 = v0 + (za.x - v0) * 0.5;
        v1 = v1 + (za.y - v1) * 0.5;
        v2 = v2 + (zc.x - v2) * 0.5;
        v3 = v3 + (zc.y - v3) * 0.5;
        bool s0 = (v0 >= 1.0), s1 = (v1 >= 1.0);
        bool s2 = (v2 >= 1.0), s3 = (v3 >= 1.0);
        float4 o;
        o.x = s0 ? 1.0f : 0.0f;
        o.y = s1 ? 1.0f : 0.0f;
        o.z = s2 ? 1.0f : 0.0f;
        o.w = s3 ? 1.0f : 0.0f;
        *(float4*)(out + (size_t)t * NPLANE + n) = o;
        v0 = s0 ? 0.0 : v0;
        v1 = s1 ? 0.0 : v1;
        v2 = s2 ? 0.0 : v2;
        v3 = s3 ? 0.0 : v3;
    }
}

// ---- ultimate fallback: R2 fused kernel, if ws too small ----
__global__ __launch_bounds__(256, 2)
void convlif_f64(const float* __restrict__ x, const float* __restrict__ Wt,
                 float* __restrict__ out) {
    __shared__ double xs[CIN * VXS_ROW];
    const int tid = threadIdx.x;
    const int pt = tid & 15;
    const int cg = tid >> 4;
    const int w0 = blockIdx.x * VTILE_W;
    const int h0 = blockIdx.y * VTILE_H;
    const int b = blockIdx.z;
    const int co_base = cg * 8;
    double v[32];
#pragma unroll
    for (int i = 0; i < 32; ++i) v[i] = 0.0;
    for (int t = 0; t < TT; ++t) {
        __syncthreads();
        const float* xb = x + (size_t)(t * BB + b) * (CIN * HH * WW);
        for (int idx = tid; idx < CIN * VXS_ROW; idx += 256) {
            int ci = idx / VXS_ROW;
            int rem = idx - ci * VXS_ROW;
            int hh = rem / VXS_W;
            int ww2 = rem - hh * VXS_W;
            int gh = h0 - 1 + hh;
            int gw = w0 - 1 + ww2;
            double val = 0.0;
            if (gh >= 0 && gh < HH && gw >= 0 && gw < WW)
                val = (double)xb[ci * (HH * WW) + gh * WW + gw];
            xs[idx] = val;
        }
        __syncthreads();
        double acc[32];
#pragma unroll
        for (int i = 0; i < 32; ++i) acc[i] = 0.0;
        for (int ci = 0; ci < CIN; ++ci) {
            const float* wr = Wt + (size_t)co_base * (CIN * 9) + ci * 9;
            const double* xr = xs + ci * VXS_ROW;
#pragma unroll
            for (int kh = 0; kh < 3; ++kh) {
#pragma unroll
                for (int kw = 0; kw < 3; ++kw) {
                    double wv[8];
#pragma unroll
                    for (int i = 0; i < 8; ++i)
                        wv[i] = (double)wr[i * (CIN * 9) + kh * 3 + kw];
                    double xv[4];
#pragma unroll
                    for (int j = 0; j < 4; ++j)
                        xv[j] = xr[(j + kh) * VXS_W + pt + kw];
#pragma unroll
                    for (int i = 0; i < 8; ++i) {
#pragma unroll
                        for (int j = 0; j < 4; ++j)
                            acc[i * 4 + j] = fma(wv[i], xv[j], acc[i * 4 + j]);
                    }
                }
            }
        }
        float* ob = out + (size_t)(t * BB + b) * (COUT * HH * WW);
#pragma unroll
        for (int i = 0; i < 8; ++i) {
#pragma unroll
            for (int j = 0; j < 4; ++j) {
                int k = i * 4 + j;
                double vv = v[k] + (acc[k] - v[k]) * 0.5;
                bool s = (vv >= 1.0);
                ob[(size_t)(co_base + i) * (HH * WW) + (h0 + j) * WW + (w0 + pt)]
                    = s ? 1.0f : 0.0f;
                v[k] = s ? 0.0 : vv;
            }
        }
    }
}

extern "C" void kernel_launch(void* const* d_in, const int* in_sizes, int n_in,
                              void* d_out, int out_size, void* d_ws, size_t ws_size,
                              hipStream_t stream) {
    const float* x = (const float*)d_in[0];
    const float* Wt = (const float*)d_in[1];
    float* out = (float*)d_out;
    if (ws_size >= WS_NEED) {
        double* wd = (double*)d_ws;
        double* z = (double*)((char*)d_ws + W_BYTES);
        int* flag = (int*)((char*)d_ws + FLAG_OFF);
        mfma_probe<<<1, 64, 0, stream>>>(flag);
        wconv_f64<<<(W_ELEMS + 255) / 256, 256, 0, stream>>>(Wt, wd);
        dim3 mgrid(WW / PW, HH / PH, 2 * TT * BB);
        conv_mfma<<<mgrid, 256, 0, stream>>>(x, wd, z, flag);
        dim3 vgrid(WW / VTILE_W, HH / VTILE_H, TT * BB);
        conv_f64<<<vgrid, 256, 0, stream>>>(x, wd, z, flag);
        lif_scan<<<NPLANE / 4 / 256, 256, 0, stream>>>(z, out);
    } else {
        dim3 grid(WW / VTILE_W, HH / VTILE_H, BB);
        convlif_f64<<<grid, 256, 0, stream>>>(x, Wt, out);
    }
}

// Round 8
// 1920.907 us; speedup vs baseline: 1.2658x; 1.2658x over previous
//
#include <hip/hip_runtime.h>
#include <math.h>

// x: [T=8, B=16, Cin=64, H=64, W=64] fp32
// W: [Cout=128, Cin=64, 3, 3] fp32
// out: spikes [T, B, Cout, H, W] fp32 (0.0 / 1.0)
//
// Precision: output is Heaviside(v-1) vs precision-neutral (fp64) numpy ref;
// all conv accumulation + LIF decisions must be fp64 (R2: absmax 0.0).
//
// R6: f64 MFMA + runtime-probed D layout -> MfmaUtil 57.5%, conv 1832 us.
// R7 lesson: fp32 LDS + cvt between ds_read and mfma stalls every K-step
// (wait forced before the MFMA burst) -> keep LDS fp64, load feeds MFMA.
// R8: double-buffered fp64 LDS (2 x 23 KB -> 3 blocks/CU); chunk c+1's x is
// global-loaded into 12 regs/thread BEFORE chunk c's 36-K-step MFMA loop
// (latency covered), then cvt+ds_write_b64 + ONE barrier per chunk.
#define TT 8
#define BB 16
#define CIN 64
#define COUT 128
#define HH 64
#define WW 64

#define PW 16
#define PH 8
#define XS_W2 (PW + 2)                     // 18
#define XS_H2 (PH + 2)                     // 10
#define XS_ROW (XS_H2 * XS_W2)             // 180 doubles per ci
#define CI_CHUNK 16
#define XS_CH (CI_CHUNK * XS_ROW)          // 2880 doubles = 23 KB per buffer

#define W_ELEMS (CIN * 9 * COUT)           // 73728
#define W_BYTES ((size_t)W_ELEMS * 8)      // 589824
#define NPLANE (BB * COUT * HH * WW)       // 8388608 per t-plane
#define Z_BYTES ((size_t)TT * NPLANE * 8)  // 512 MB
#define FLAG_OFF (W_BYTES + Z_BYTES)
#define WS_NEED (FLAG_OFF + 16)

typedef double d4 __attribute__((ext_vector_type(4)));

// ---- prologue: W [co][ci][kh][kw] fp32 -> wd [k=(ci,kh,kw)][co] fp64 ----
__global__ void wconv_f64(const float* __restrict__ Wt, double* __restrict__ wd) {
    int idx = blockIdx.x * 256 + threadIdx.x;
    if (idx >= W_ELEMS) return;
    int co = idx & 127;
    int k = idx >> 7;
    int ci = k / 9;
    int r = k - ci * 9;
    wd[idx] = (double)Wt[((size_t)co * CIN + ci) * 9 + r];
}

// ---- probe: discover f64 MFMA D layout on this hardware (R6-proven) ----
__global__ void mfma_probe(int* __restrict__ flag) {
    int lane = threadIdx.x;
    int l15 = lane & 15, q = lane >> 4;
    double a = (double)(l15 * 4 + q + 1);             // A[m][k] = m*4+k+1
    double b = (double)(q * 16 + l15 + 1) * 0.001;    // B[k][n] = (k*16+n+1)/1000
    d4 acc = (d4)(0.0);
    acc = __builtin_amdgcn_mfma_f64_16x16x4f64(a, b, acc, 0, 0, 0);
    bool ok0 = true, ok1 = true, ok2 = true, ok3 = true;
    for (int d = 0; d < 4; ++d) {
        double e0 = 0, e1 = 0, e2 = 0, e3 = 0;
        for (int k = 0; k < 4; ++k) {
            e0 += (double)((4 * q + d) * 4 + k + 1) * ((double)(k * 16 + l15 + 1) * 0.001);
            e1 += (double)(l15 * 4 + k + 1) * ((double)(k * 16 + 4 * q + d + 1) * 0.001);
            e2 += (double)((q + 4 * d) * 4 + k + 1) * ((double)(k * 16 + l15 + 1) * 0.001);
            e3 += (double)(l15 * 4 + k + 1) * ((double)(k * 16 + q + 4 * d + 1) * 0.001);
        }
        ok0 &= fabs(acc[d] - e0) < 1e-9;
        ok1 &= fabs(acc[d] - e1) < 1e-9;
        ok2 &= fabs(acc[d] - e2) < 1e-9;
        ok3 &= fabs(acc[d] - e3) < 1e-9;
    }
    int f = __all(ok0) ? 0 : (__all(ok1) ? 1 : (__all(ok2) ? 2 : (__all(ok3) ? 3 : 4)));
    if (lane == 0) *flag = f;
}

// ---- phase 1a: implicit-GEMM conv via fp64 MFMA, dbuf LDS pipeline ----
// Block: 4 waves, 64 co x 128 px per block, one image.
// Grid: (4, 8, 2 * 128) = 8192 blocks.
__global__ __launch_bounds__(256)
void conv_mfma(const float* __restrict__ x, const double* __restrict__ wd,
               double* __restrict__ z, const int* __restrict__ flag) {
    const int lay = *flag;
    if (lay > 3) return;

    __shared__ double xs[2][XS_CH];      // 46 KB total

    const int tid = threadIdx.x;
    const int lane = tid & 63;
    const int wave = tid >> 6;
    const int l15 = lane & 15;
    const int koff = lane >> 4;
    const int cslice = wave & 1;
    const int pslice = wave >> 1;
    const int hbase = 4 * pslice;

    const int w0 = blockIdx.x * PW;
    const int h0 = blockIdx.y * PH;
    const int cob = (blockIdx.z & 1) * 64;
    const int tb = blockIdx.z >> 1;
    const int co_w = cob + 32 * cslice;

    const float* xb = x + (size_t)tb * (CIN * HH * WW);

    // ---- stage chunk 0 (regs -> cvt -> LDS buf0) ----
    float stg[12];
#pragma unroll
    for (int i = 0; i < 12; ++i) {
        int idx = tid + i * 256;
        float v = 0.0f;
        if (idx < XS_CH) {
            int cil = idx / XS_ROW;
            int rem = idx - cil * XS_ROW;
            int hr = rem / XS_W2;
            int wr = rem - hr * XS_W2;
            int gh = h0 - 1 + hr;
            int gw = w0 - 1 + wr;
            if (gh >= 0 && gh < HH && gw >= 0 && gw < WW)
                v = xb[cil * (HH * WW) + gh * WW + gw];
        }
        stg[i] = v;
    }
#pragma unroll
    for (int i = 0; i < 12; ++i) {
        int idx = tid + i * 256;
        if (idx < XS_CH) xs[0][idx] = (double)stg[i];
    }
    __syncthreads();

    d4 acc[2][4];
#pragma unroll
    for (int i = 0; i < 2; ++i)
#pragma unroll
        for (int j = 0; j < 4; ++j)
            acc[i][j] = (d4)(0.0);

    for (int c = 0; c < 4; ++c) {
        const double* buf = xs[c & 1];
        const int kbase = c * (CI_CHUNK * 9);   // global k offset for wd

        // ---- issue chunk c+1 global loads BEFORE the K-loop (latency cover) ----
        if (c < 3) {
            int ccn = (c + 1) * CI_CHUNK;
#pragma unroll
            for (int i = 0; i < 12; ++i) {
                int idx = tid + i * 256;
                float v = 0.0f;
                if (idx < XS_CH) {
                    int cil = idx / XS_ROW;
                    int rem = idx - cil * XS_ROW;
                    int hr = rem / XS_W2;
                    int wr = rem - hr * XS_W2;
                    int gh = h0 - 1 + hr;
                    int gw = w0 - 1 + wr;
                    if (gh >= 0 && gh < HH && gw >= 0 && gw < WW)
                        v = xb[(ccn + cil) * (HH * WW) + gh * WW + gw];
                }
                stg[i] = v;
            }
        }

        // ---- K-loop: 144 k-values in 36 steps of 4, reg double-buffered ----
        double a_cur0, a_cur1, b_cur0, b_cur1, b_cur2, b_cur3;
        double a_nxt0, a_nxt1, b_nxt0, b_nxt1, b_nxt2, b_nxt3;
        {
            int kl = koff;
            int cil = kl / 9;
            int r = kl - cil * 9;
            int kh = r / 3;
            int kw = r - kh * 3;
            const double* ap = wd + (size_t)(kbase + kl) * COUT + co_w + l15;
            a_cur0 = ap[0]; a_cur1 = ap[16];
            const double* bp = buf + cil * XS_ROW + (hbase + kh) * XS_W2 + l15 + kw;
            b_cur0 = bp[0]; b_cur1 = bp[XS_W2];
            b_cur2 = bp[2 * XS_W2]; b_cur3 = bp[3 * XS_W2];
        }
        for (int ks = 0; ks < 35; ++ks) {
            {
                int kl = (ks + 1) * 4 + koff;
                int cil = kl / 9;
                int r = kl - cil * 9;
                int kh = r / 3;
                int kw = r - kh * 3;
                const double* ap = wd + (size_t)(kbase + kl) * COUT + co_w + l15;
                a_nxt0 = ap[0]; a_nxt1 = ap[16];
                const double* bp = buf + cil * XS_ROW + (hbase + kh) * XS_W2 + l15 + kw;
                b_nxt0 = bp[0]; b_nxt1 = bp[XS_W2];
                b_nxt2 = bp[2 * XS_W2]; b_nxt3 = bp[3 * XS_W2];
            }
            acc[0][0] = __builtin_amdgcn_mfma_f64_16x16x4f64(a_cur0, b_cur0, acc[0][0], 0, 0, 0);
            acc[0][1] = __builtin_amdgcn_mfma_f64_16x16x4f64(a_cur0, b_cur1, acc[0][1], 0, 0, 0);
            acc[0][2] = __builtin_amdgcn_mfma_f64_16x16x4f64(a_cur0, b_cur2, acc[0][2], 0, 0, 0);
            acc[0][3] = __builtin_amdgcn_mfma_f64_16x16x4f64(a_cur0, b_cur3, acc[0][3], 0, 0, 0);
            acc[1][0] = __builtin_amdgcn_mfma_f64_16x16x4f64(a_cur1, b_cur0, acc[1][0], 0, 0, 0);
            acc[1][1] = __builtin_amdgcn_mfma_f64_16x16x4f64(a_cur1, b_cur1, acc[1][1], 0, 0, 0);
            acc[1][2] = __builtin_amdgcn_mfma_f64_16x16x4f64(a_cur1, b_cur2, acc[1][2], 0, 0, 0);
            acc[1][3] = __builtin_amdgcn_mfma_f64_16x16x4f64(a_cur1, b_cur3, acc[1][3], 0, 0, 0);
            a_cur0 = a_nxt0; a_cur1 = a_nxt1;
            b_cur0 = b_nxt0; b_cur1 = b_nxt1; b_cur2 = b_nxt2; b_cur3 = b_nxt3;
        }
        acc[0][0] = __builtin_amdgcn_mfma_f64_16x16x4f64(a_cur0, b_cur0, acc[0][0], 0, 0, 0);
        acc[0][1] = __builtin_amdgcn_mfma_f64_16x16x4f64(a_cur0, b_cur1, acc[0][1], 0, 0, 0);
        acc[0][2] = __builtin_amdgcn_mfma_f64_16x16x4f64(a_cur0, b_cur2, acc[0][2], 0, 0, 0);
        acc[0][3] = __builtin_amdgcn_mfma_f64_16x16x4f64(a_cur0, b_cur3, acc[0][3], 0, 0, 0);
        acc[1][0] = __builtin_amdgcn_mfma_f64_16x16x4f64(a_cur1, b_cur0, acc[1][0], 0, 0, 0);
        acc[1][1] = __builtin_amdgcn_mfma_f64_16x16x4f64(a_cur1, b_cur1, acc[1][1], 0, 0, 0);
        acc[1][2] = __builtin_amdgcn_mfma_f64_16x16x4f64(a_cur1, b_cur2, acc[1][2], 0, 0, 0);
        acc[1][3] = __builtin_amdgcn_mfma_f64_16x16x4f64(a_cur1, b_cur3, acc[1][3], 0, 0, 0);

        // ---- write chunk c+1 into the other buffer; ONE barrier per chunk.
        // Safe: buf[(c+1)&1] was last read in K-loop(c-1), which all waves
        // completed before the barrier at the end of iteration c-1.
        if (c < 3) {
#pragma unroll
            for (int i = 0; i < 12; ++i) {
                int idx = tid + i * 256;
                if (idx < XS_CH) xs[(c + 1) & 1][idx] = (double)stg[i];
            }
            __syncthreads();
        }
    }

    // ---- store z with probed D layout ----
    double* zb = z + (size_t)tb * (COUT * HH * WW);
#pragma unroll
    for (int i2 = 0; i2 < 2; ++i2) {
        int cw = co_w + 16 * i2;
#pragma unroll
        for (int jt = 0; jt < 4; ++jt) {
            int h = h0 + hbase + jt;
            d4 a = acc[i2][jt];
            if (lay == 0) {          // D[m=4q+d][n=l15]
#pragma unroll
                for (int d = 0; d < 4; ++d)
                    zb[(size_t)(cw + 4 * koff + d) * (HH * WW) + h * WW + w0 + l15] = a[d];
            } else if (lay == 1) {   // D[m=l15][n=4q+d]
                *(d4*)&zb[(size_t)(cw + l15) * (HH * WW) + h * WW + w0 + 4 * koff] = a;
            } else if (lay == 2) {   // D[m=q+4d][n=l15]
#pragma unroll
                for (int d = 0; d < 4; ++d)
                    zb[(size_t)(cw + koff + 4 * d) * (HH * WW) + h * WW + w0 + l15] = a[d];
            } else {                 // D[m=l15][n=q+4d]
#pragma unroll
                for (int d = 0; d < 4; ++d)
                    zb[(size_t)(cw + l15) * (HH * WW) + h * WW + w0 + koff + 4 * d] = a[d];
            }
        }
    }
}

// ---- phase 1b: trusted vector-fp64 conv (runs iff probe found no layout) ----
#define VTILE_H 4
#define VTILE_W 16
#define VXS_W (VTILE_W + 2)
#define VXS_ROW ((VTILE_H + 2) * VXS_W)    // 108 per ci
#define VXS_N (CIN * VXS_ROW)
__global__ __launch_bounds__(256, 2)
void conv_f64(const float* __restrict__ x, const double* __restrict__ wd,
              double* __restrict__ z, const int* __restrict__ flag) {
    if (*flag <= 3) return;
    __shared__ float xs[VXS_N];

    const int tid = threadIdx.x;
    const int pt = tid & 15;
    const int cg = tid >> 4;
    const int w0 = blockIdx.x * VTILE_W;
    const int h0 = blockIdx.y * VTILE_H;
    const int tb = blockIdx.z;
    const int co_base = cg * 8;

    const float* xb = x + (size_t)tb * (CIN * HH * WW);
    for (int idx = tid; idx < VXS_N; idx += 256) {
        int ci = idx / VXS_ROW;
        int rem = idx - ci * VXS_ROW;
        int hh = rem / VXS_W;
        int ww2 = rem - hh * VXS_W;
        int gh = h0 - 1 + hh;
        int gw = w0 - 1 + ww2;
        float val = 0.0f;
        if (gh >= 0 && gh < HH && gw >= 0 && gw < WW)
            val = xb[ci * (HH * WW) + gh * WW + gw];
        xs[idx] = val;
    }
    __syncthreads();

    double acc[32];
#pragma unroll
    for (int i = 0; i < 32; ++i) acc[i] = 0.0;

    for (int ci = 0; ci < CIN; ++ci) {
        const float* xr = xs + ci * VXS_ROW;
        const double* wrow = wd + (size_t)(ci * 9) * COUT + co_base;
#pragma unroll
        for (int kh = 0; kh < 3; ++kh) {
#pragma unroll
            for (int kw = 0; kw < 3; ++kw) {
                const double2* wp = (const double2*)(wrow + (kh * 3 + kw) * COUT);
                double2 w01 = wp[0], w23 = wp[1], w45 = wp[2], w67 = wp[3];
                double wv[8] = {w01.x, w01.y, w23.x, w23.y,
                                w45.x, w45.y, w67.x, w67.y};
                double xv[4];
#pragma unroll
                for (int j = 0; j < 4; ++j)
                    xv[j] = (double)xr[(j + kh) * VXS_W + pt + kw];
#pragma unroll
                for (int i = 0; i < 8; ++i) {
#pragma unroll
                    for (int j = 0; j < 4; ++j)
                        acc[i * 4 + j] = fma(wv[i], xv[j], acc[i * 4 + j]);
                }
            }
        }
    }

    double* zb = z + (size_t)tb * (COUT * HH * WW);
#pragma unroll
    for (int i = 0; i < 8; ++i) {
#pragma unroll
        for (int j = 0; j < 4; ++j)
            zb[(size_t)(co_base + i) * (HH * WW) + (h0 + j) * WW + (w0 + pt)]
                = acc[i * 4 + j];
    }
}

// ---- phase 2: LIF scan over t, 4 elems/thread ----
__global__ __launch_bounds__(256)
void lif_scan(const double* __restrict__ z, float* __restrict__ out) {
    size_t n = ((size_t)blockIdx.x * 256 + threadIdx.x) * 4;
    double v0 = 0.0, v1 = 0.0, v2 = 0.0, v3 = 0.0;
#pragma unroll
    for (int t = 0; t < TT; ++t) {
        const double* zp = z + (size_t)t * NPLANE + n;
        double2 za = *(const double2*)(zp);
        double2 zc = *(const double2*)(zp + 2);
        v0 = v0 + (za.x - v0) * 0.5;
        v1 = v1 + (za.y - v1) * 0.5;
        v2 = v2 + (zc.x - v2) * 0.5;
        v3 = v3 + (zc.y - v3) * 0.5;
        bool s0 = (v0 >= 1.0), s1 = (v1 >= 1.0);
        bool s2 = (v2 >= 1.0), s3 = (v3 >= 1.0);
        float4 o;
        o.x = s0 ? 1.0f : 0.0f;
        o.y = s1 ? 1.0f : 0.0f;
        o.z = s2 ? 1.0f : 0.0f;
        o.w = s3 ? 1.0f : 0.0f;
        *(float4*)(out + (size_t)t * NPLANE + n) = o;
        v0 = s0 ? 0.0 : v0;
        v1 = s1 ? 0.0 : v1;
        v2 = s2 ? 0.0 : v2;
        v3 = s3 ? 0.0 : v3;
    }
}

// ---- ultimate fallback: R2 fused kernel, if ws too small ----
__global__ __launch_bounds__(256, 2)
void convlif_f64(const float* __restrict__ x, const float* __restrict__ Wt,
                 float* __restrict__ out) {
    __shared__ double xs[CIN * VXS_ROW];
    const int tid = threadIdx.x;
    const int pt = tid & 15;
    const int cg = tid >> 4;
    const int w0 = blockIdx.x * VTILE_W;
    const int h0 = blockIdx.y * VTILE_H;
    const int b = blockIdx.z;
    const int co_base = cg * 8;
    double v[32];
#pragma unroll
    for (int i = 0; i < 32; ++i) v[i] = 0.0;
    for (int t = 0; t < TT; ++t) {
        __syncthreads();
        const float* xb = x + (size_t)(t * BB + b) * (CIN * HH * WW);
        for (int idx = tid; idx < CIN * VXS_ROW; idx += 256) {
            int ci = idx / VXS_ROW;
            int rem = idx - ci * VXS_ROW;
            int hh = rem / VXS_W;
            int ww2 = rem - hh * VXS_W;
            int gh = h0 - 1 + hh;
            int gw = w0 - 1 + ww2;
            double val = 0.0;
            if (gh >= 0 && gh < HH && gw >= 0 && gw < WW)
                val = (double)xb[ci * (HH * WW) + gh * WW + gw];
            xs[idx] = val;
        }
        __syncthreads();
        double acc[32];
#pragma unroll
        for (int i = 0; i < 32; ++i) acc[i] = 0.0;
        for (int ci = 0; ci < CIN; ++ci) {
            const float* wr = Wt + (size_t)co_base * (CIN * 9) + ci * 9;
            const double* xr = xs + ci * VXS_ROW;
#pragma unroll
            for (int kh = 0; kh < 3; ++kh) {
#pragma unroll
                for (int kw = 0; kw < 3; ++kw) {
                    double wv[8];
#pragma unroll
                    for (int i = 0; i < 8; ++i)
                        wv[i] = (double)wr[i * (CIN * 9) + kh * 3 + kw];
                    double xv[4];
#pragma unroll
                    for (int j = 0; j < 4; ++j)
                        xv[j] = xr[(j + kh) * VXS_W + pt + kw];
#pragma unroll
                    for (int i = 0; i < 8; ++i) {
#pragma unroll
                        for (int j = 0; j < 4; ++j)
                            acc[i * 4 + j] = fma(wv[i], xv[j], acc[i * 4 + j]);
                    }
                }
            }
        }
        float* ob = out + (size_t)(t * BB + b) * (COUT * HH * WW);
#pragma unroll
        for (int i = 0; i < 8; ++i) {
#pragma unroll
            for (int j = 0; j < 4; ++j) {
                int k = i * 4 + j;
                double vv = v[k] + (acc[k] - v[k]) * 0.5;
                bool s = (vv >= 1.0);
                ob[(size_t)(co_base + i) * (HH * WW) + (h0 + j) * WW + (w0 + pt)]
                    = s ? 1.0f : 0.0f;
                v[k] = s ? 0.0 : vv;
            }
        }
    }
}

extern "C" void kernel_launch(void* const* d_in, const int* in_sizes, int n_in,
                              void* d_out, int out_size, void* d_ws, size_t ws_size,
                              hipStream_t stream) {
    const float* x = (const float*)d_in[0];
    const float* Wt = (const float*)d_in[1];
    float* out = (float*)d_out;
    if (ws_size >= WS_NEED) {
        double* wd = (double*)d_ws;
        double* z = (double*)((char*)d_ws + W_BYTES);
        int* flag = (int*)((char*)d_ws + FLAG_OFF);
        mfma_probe<<<1, 64, 0, stream>>>(flag);
        wconv_f64<<<(W_ELEMS + 255) / 256, 256, 0, stream>>>(Wt, wd);
        dim3 mgrid(WW / PW, HH / PH, 2 * TT * BB);
        conv_mfma<<<mgrid, 256, 0, stream>>>(x, wd, z, flag);
        dim3 vgrid(WW / VTILE_W, HH / VTILE_H, TT * BB);
        conv_f64<<<vgrid, 256, 0, stream>>>(x, wd, z, flag);
        lif_scan<<<NPLANE / 4 / 256, 256, 0, stream>>>(z, out);
    } else {
        dim3 grid(WW / VTILE_W, HH / VTILE_H, BB);
        convlif_f64<<<grid, 256, 0, stream>>>(x, Wt, out);
    }
}